// Round 8
// baseline (341.451 us; speedup 1.0000x reference)
//
#include <hip/hip_runtime.h>
#include <cstdint>
#include <cstddef>

#pragma clang fp contract(off)

#define BATCH    8
#define NANCH    261888
#define PRE_NMS  6000
#define PROP     1000
#define SORTN    8192
#define NSLOT    6144          /* 6 * 1024 */
#define MROW     96            /* u64 words per suppression row (94 used + 2 pad) */
#define NW       94            /* suppression words per batch (6000/64 rounded up) */
#define CHUNK_W  32            /* words computed+scanned in the fast first pass */
#define NZCAP    128           /* LDS-stashed nonzero rows (capped scan) */
#define NPAIR    130944        /* NANCH / 2 */
#define CBLK     64            /* blocks per batch for front kernel */
#define CPAIR    2046          /* NPAIR / CBLK */
#define KCAP     1024          /* compact LDS staging capacity */
#define SCORE_THRES_BITS 0x3F000000u   /* bits of 0.5f */
#define EPS_F    1e-8f
/* midpoint between pred(0.7f) and 0.7f = 23488101 * 2^-25, exact in double.
   RN(inter/denom) >= 0.7f  <=>  inter > M_D * denom  (exact: 25b x 24b product;
   tie rounds to even = pred(0.7f), so strict > is correct). */
#define M_D      0.6999999582767486572265625

typedef unsigned long long ull;
typedef unsigned int u32;

// ---------------------------------------------------------------------------
// R17: the pipeline is fused into TWO kernels (was 8) — ~90us of per-dispatch
// gap overhead was the dominant cost. Cross-block phase handoffs use
// per-batch atomic tickets + precise agent-scope fences:
//   release (buffer_wbl2, no inv) before publishing a ticket,
//   acquire (buffer_inv) after observing it.
// Co-residency (required for spin-safety, per guide G16 capacity rule):
//   front: 512 blocks x 256 thr, ~10KB LDS -> >=2 blocks/CU (launch_bounds).
//   back : 256 blocks x 1024 thr, 156.4KB LDS -> exactly 1 block/CU x 256 CUs.
// ---------------------------------------------------------------------------

__device__ __forceinline__ void fence_release_agent()
{
    __builtin_amdgcn_fence(__ATOMIC_RELEASE, "agent");
}
__device__ __forceinline__ void fence_acquire_agent()
{
    __builtin_amdgcn_fence(__ATOMIC_ACQUIRE, "agent");
}

// ---------------------------------------------------------------------------
// FRONT kernel: hist -> findT/binbase -> bucketed compact -> rank+decode.
// grid (CBLK, BATCH) x 256. Per-batch tickets; batches pipeline independently.
// ---------------------------------------------------------------------------
__global__ __launch_bounds__(256, 2)
void front_kernel(const float* __restrict__ rpn_probs,
                  const float* __restrict__ rpn_bbox,
                  const float* __restrict__ anchors,
                  u32* __restrict__ ghist, u32* __restrict__ done,
                  u32* __restrict__ Tc, u32* __restrict__ binbase,
                  u32* __restrict__ cntp, u32* __restrict__ bincnt,
                  ull* __restrict__ selbuf, u32* __restrict__ done2,
                  float4* __restrict__ boxes_ws, float* __restrict__ area_ws,
                  ull* __restrict__ alive_ws)
{
    const int t    = threadIdx.x;
    const int lane = t & 63;
    const int b    = blockIdx.y;
    const int x    = blockIdx.x;

    __shared__ u32 h[132];
    __shared__ u32 s_old, s_T, s_n;
    __shared__ ull kbuf[KCAP];
    __shared__ u32 s_hist[132];
    __shared__ u32 s_base[132];
    __shared__ u32 s_bb[132];

    // ================= phase H: histogram =================
    if (t < 132) h[t] = 0u;
    __syncthreads();

    const float4* p4 = reinterpret_cast<const float4*>(rpn_probs + (size_t)b * NANCH * 2);
    const int p0 = x * CPAIR;
    for (int i = t; i < CPAIR; i += 256) {
        float4 v = p4[p0 + i];                 // scores of anchors 2p, 2p+1 in .y/.w
        u32 k0 = __float_as_uint(v.y);
        u32 k1 = __float_as_uint(v.w);
        if (k0 >= 0x3F000000u) atomicAdd(&h[min((k0 >> 16) - 0x3F00u, 128u)], 1u);
        if (k1 >= 0x3F000000u) atomicAdd(&h[min((k1 >> 16) - 0x3F00u, 128u)], 1u);
    }
    __syncthreads();
    if (t < 129 && h[t]) atomicAdd(&ghist[(b << 8) + t], h[t]);

    // order: ghist atomics performed before the done++ ticket (atomics reach
    // the coherent point when vmcnt drains; no cache maintenance needed).
    asm volatile("s_waitcnt vmcnt(0)" ::: "memory");
    if (t == 0) s_old = atomicAdd(&done[b], 1u);
    __syncthreads();
    if (s_old == CBLK - 1) {
        // last block for this batch: all ghist atomics globally performed
        if (t < 129) h[t] = atomicAdd(&ghist[(b << 8) + t], 0u);   // coherent read
        __syncthreads();
        if (t == 0) {
            u32* bb = binbase + b * 132;
            u32 run = 0; int binT = -1; u32 Cv = 0;
            for (int i = 128; i >= 0; --i) {
                bb[i] = run;                    // # keys in bins strictly above i
                run += h[i];
                if (binT < 0 && run >= PRE_NMS) { binT = i; Cv = run; }
            }
            u32 T;
            if (binT < 0)         { T = 0x3F000000u; Cv = run; }  // unreachable
            else if (binT == 128)   T = 0x3F800000u;
            else                    T = 0x3F000000u + ((u32)binT << 16);
            cntp[b << 6] = Cv;
            fence_release_agent();              // publish binbase/cntp
            atomicExch(&Tc[b], T);              // release flag (never 0 when set)
        }
    }

    // ================= wait for Tc[b] =================
    if (t == 0) {
        u32 T;
        while ((T = atomicAdd(&Tc[b], 0u)) == 0u) __builtin_amdgcn_s_sleep(8);
        s_T = T;
    }
    __syncthreads();
    fence_acquire_agent();                      // see binbase/cntp
    if (t < 132) s_bb[t] = binbase[b * 132 + t];
    if (t == 0) s_n = 0u;
    if (t < 132) s_hist[t] = 0u;
    __syncthreads();
    const u32 T = s_T;

    // ================= phase C: bucketed compact =================
    ull* sb = selbuf + (size_t)b * SORTN;
    u32* bc = bincnt + b * 132;

    for (int i = t; i < CPAIR; i += 256) {
        float4 v = p4[p0 + i];
        const int n0 = (p0 + i) << 1;
        #pragma unroll
        for (int e = 0; e < 2; ++e) {
            u32 k = __float_as_uint(e ? v.w : v.y);
            bool s0 = (k >= T);
            ull m = __ballot(s0 ? 1 : 0);
            if (!m) continue;                                  // wave-uniform
            int ldr = __ffsll(m) - 1;
            u32 base = 0;
            if (lane == ldr) base = atomicAdd(&s_n, (u32)__popcll(m));
            base = __shfl(base, ldr);
            u32 off = base + (u32)__popcll(m & ((1ull << lane) - 1ull));
            if (s0) {
                ull pk = ((ull)(~k) << 32) | (ull)(u32)(n0 + e);
                if (off < KCAP) {
                    kbuf[off] = pk;
                } else {
                    // exact spill (unreachable at ~100 staged/block)
                    u32 bin = min((k >> 16) - 0x3F00u, 128u);
                    u32 pos = s_bb[bin] + atomicAdd(&bc[bin], 1u);
                    if (pos < SORTN) sb[pos] = pk;
                }
            }
        }
    }
    __syncthreads();
    const u32 nn = min(s_n, (u32)KCAP);

    // per-block bin histogram
    for (u32 j = t; j < nn; j += 256) {
        u32 k = ~(u32)(kbuf[j] >> 32);
        atomicAdd(&s_hist[min((k >> 16) - 0x3F00u, 128u)], 1u);
    }
    __syncthreads();
    // reserve this block's range in each active bin (one global atomic each)
    if (t < 132 && s_hist[t]) s_base[t] = atomicAdd(&bc[t], s_hist[t]);
    __syncthreads();
    if (t < 132) s_hist[t] = 0u;      // reuse as local position counters
    __syncthreads();
    // scatter
    for (u32 j = t; j < nn; j += 256) {
        ull kv = kbuf[j];
        u32 k = ~(u32)(kv >> 32);
        u32 bin = min((k >> 16) - 0x3F00u, 128u);
        u32 local = atomicAdd(&s_hist[bin], 1u);
        u32 pos = s_bb[bin] + s_base[bin] + local;
        if (pos < SORTN) sb[pos] = kv;
    }

    // release selbuf stores, then ticket
    fence_release_agent();
    if (t == 0) atomicAdd(&done2[b], 1u);

    // ================= wait for all compact of batch b =================
    if (t == 0) {
        while (atomicAdd(&done2[b], 0u) < (u32)CBLK) __builtin_amdgcn_s_sleep(8);
    }
    __syncthreads();
    fence_acquire_agent();                      // see selbuf

    // ================= phase R: bucketed rank + decode =================
    const u32 C = min(cntp[b << 6], (u32)SORTN);
    const int i = (x << 7) + t;                 // 64 blocks x 128 slots = 8192
    if (t >= 128 || i >= (int)C) return;

    const ull mykey = sb[i];
    const u32 key = ~(u32)(mykey >> 32);
    const u32 n   = (u32)(mykey & 0xFFFFFFFFull);
    const u32 bin = min((key >> 16) - 0x3F00u, 128u);
    const u32 lo  = s_bb[bin];
    const u32 cb  = min(ghist[(b << 8) + bin], (u32)SORTN - lo);

    const ull* base = sb + lo;
    int local = 0;
    u32 j = 0;
    for (; j + 8 <= cb; j += 8) {
        #pragma unroll
        for (int u = 0; u < 8; ++u) local += (base[j + u] < mykey) ? 1 : 0;
    }
    for (; j < cb; ++j) local += (base[j] < mykey) ? 1 : 0;
    const int rank = (int)lo + local;

    if (rank < PRE_NMS) {
        const float4* bbox4 = reinterpret_cast<const float4*>(rpn_bbox + (size_t)b * NANCH * 4);
        const float4* anc4  = reinterpret_cast<const float4*>(anchors  + (size_t)b * NANCH * 4);
        float4 a = anc4[n];
        float4 d = bbox4[n];
        float dy = d.x * 0.1f, dx = d.y * 0.1f, dh = d.z * 0.2f, dw = d.w * 0.2f;
        float hh = a.z - a.x;
        float ww = a.w - a.y;
        float cy = a.x + 0.5f * hh;
        float cx = a.y + 0.5f * ww;
        cy = cy + dy * hh;
        cx = cx + dx * ww;
        hh = hh * expf(dh);
        ww = ww * expf(dw);
        float y1 = cy - 0.5f * hh;
        float x1 = cx - 0.5f * ww;
        float y2 = y1 + hh;
        float x2 = x1 + ww;
        y1 = fminf(fmaxf(y1, 0.f), 1.f);
        x1 = fminf(fmaxf(x1, 0.f), 1.f);
        y2 = fminf(fmaxf(y2, 0.f), 1.f);
        x2 = fminf(fmaxf(x2, 0.f), 1.f);
        boxes_ws[(size_t)b * NSLOT + rank] = make_float4(y1, x1, y2, x2);
        area_ws[(size_t)b * NSLOT + rank]  = (y2 - y1) * (x2 - x1);
        if (key >= SCORE_THRES_BITS) {
            atomicOr(&alive_ws[(size_t)b * MROW + (rank >> 6)], 1ull << (rank & 63));
        }
    }
}

// ---------------------------------------------------------------------------
// iou word-block: stage cols, compute suppression words kbeg..kend-1 for the
// 64 rows of word-block j (16 waves x 4 rows), publish nzmask bits.
// ---------------------------------------------------------------------------
__device__ void iou_block(const float4* __restrict__ bws_b,
                          const float* __restrict__ aws_b,
                          ull* __restrict__ mat_b, ull* __restrict__ nzm_b,
                          int j, int kbeg, int kend,
                          float4* sbox, float* sarea)
{
    const int t    = threadIdx.x;
    const int lane = t & 63;
    const int wv   = t >> 6;
    const int base = j << 6;
    const int nst  = (kend << 6) - base;

    for (int i = t; i < nst; i += 1024) { sbox[i] = bws_b[base + i]; sarea[i] = aws_b[base + i]; }
    __syncthreads();

    const int r0 = base + (wv << 2);
    if (r0 < PRE_NMS) {
        float4 P[4];
        float  PA[4];
        #pragma unroll
        for (int qi = 0; qi < 4; ++qi) { P[qi] = sbox[(wv << 2) + qi]; PA[qi] = sarea[(wv << 2) + qi]; }

        ull* rowp = mat_b + (size_t)r0 * MROW;
        ull acc[4] = {0ull, 0ull, 0ull, 0ull};

        for (int k = kbeg; k < kend; ++k) {
            const int ci = ((k - j) << 6) + lane;
            const float4 qb = sbox[ci];
            const float  qa = sarea[ci];
            ull m[4];
            #pragma unroll
            for (int qi = 0; qi < 4; ++qi) {
                float yy1 = fmaxf(P[qi].x, qb.x);
                float xx1 = fmaxf(P[qi].y, qb.y);
                float yy2 = fminf(P[qi].z, qb.z);
                float xx2 = fminf(P[qi].w, qb.w);
                float inter = fmaxf(yy2 - yy1, 0.f) * fmaxf(xx2 - xx1, 0.f);
                float denom = ((PA[qi] + qa) - inter) + EPS_F;
                m[qi] = __ballot(((double)inter > M_D * (double)denom) ? 1 : 0);
            }
            if (k == j) {                       // diagonal word: mask away c <= r
                #pragma unroll
                for (int qi = 0; qi < 4; ++qi) {
                    int sh = (wv << 2) + qi;
                    ull keep = (sh == 63) ? 0ull : ((~0ull) << (sh + 1));
                    m[qi] &= keep;
                }
            }
            #pragma unroll
            for (int qi = 0; qi < 4; ++qi) acc[qi] |= m[qi];
            if (lane == 0) {
                #pragma unroll
                for (int qi = 0; qi < 4; ++qi) rowp[(size_t)qi * MROW + k] = m[qi];
            }
        }

        if (lane == 0) {
            u32 bits = 0;
            #pragma unroll
            for (int qi = 0; qi < 4; ++qi) if (acc[qi]) bits |= 1u << qi;
            if (bits) atomicOr(&nzm_b[j], (ull)bits << (wv << 2));
        }
    }
    __syncthreads();   // protect sbox for the caller's next staging
}

// ---------------------------------------------------------------------------
// Greedy word-walk scan, executed by WAVE 0 ONLY (barrier-free: all LDS
// traffic is wave-local; lgkmcnt ordering suffices). Same algorithm as R14.
//   FIRST=true : capped scan (words 0..CHUNK_W-1) with LDS row stash;
//                sets flags[b]=1 (success, output written) or 2 (need rest).
//   FIRST=false: full scan, on-demand global row reads; always writes output.
// ---------------------------------------------------------------------------
__device__ __forceinline__ ull shfl_xor64(ull x, int s)
{
    return (ull)__shfl_xor((long long)x, s, 64);
}

__device__ __forceinline__ ull readlane64(ull x, int l)
{
    u32 lo = (u32)__builtin_amdgcn_readlane((int)(u32)x, l);
    u32 hi = (u32)__builtin_amdgcn_readlane((int)(u32)(x >> 32), l);
    return ((ull)hi << 32) | (ull)lo;
}

template<bool FIRST>
__device__ void scan_wave(int b, int lane,
                          const float4* __restrict__ bws_b,
                          const ull* __restrict__ alive_ws,
                          const ull* __restrict__ mb,
                          const ull* __restrict__ nzm,
                          float* __restrict__ out,
                          u32* __restrict__ flags,
                          int* picks, u32* nzrows, ull* nzbuf)
{
    const int CW = FIRST ? CHUNK_W : NW;

    // lane l (<48) holds alive words 2l, 2l+1 (words 94,95 zero by construction)
    ull aw0 = 0, aw1 = 0;
    if (lane < 48) {
        const ull* aw = alive_ws + (size_t)b * MROW + 2 * lane;
        aw0 = aw[0]; aw1 = aw[1];
    }

    ull nzA = 0, nzB = 0;
    if (FIRST) { if (lane < CHUNK_W) nzA = nzm[lane]; }
    else       { if (lane < 47)      { nzA = nzm[2 * lane]; nzB = nzm[2 * lane + 1]; } }

    int excl = 0, NZ = 0;
    if (FIRST) {
        // exclusive prefix of per-word nz popcounts over lanes 0..31
        int c = (int)__popcll(nzA);
        int incl = c;
        for (int s = 1; s < 32; s <<= 1) {
            int y = __shfl_up(incl, s, 64);
            if (lane >= s) incl += y;
        }
        excl = incl - c;
        NZ = __builtin_amdgcn_readlane(incl, 31);

        // build compacted nonzero-row list (slots < NZCAP)
        {
            ull m = nzA; int r = excl;
            while (m) {
                int p = __ffsll(m) - 1; m &= m - 1ull;
                if (r < NZCAP) nzrows[r] = (u32)((lane << 6) + p);
                ++r;
            }
        }
        // stash nonzero rows (words 0..31 = 256 B each) into LDS; 4 rows/inst
        const int NP = min(NZ, NZCAP);
        if (NP > 0) {
            u32 ridA = nzrows[lane];
            u32 ridB = nzrows[64 + lane];
            const int ninst = (NP + 3) >> 2;
            for (int i = 0; i < ninst; ++i) {
                int slot = 4 * i + (lane >> 4);
                if (slot >= NP) slot = NP - 1;
                int sel = (slot & 63) << 2;
                int ra = __builtin_amdgcn_ds_bpermute(sel, (int)ridA);
                int rb = __builtin_amdgcn_ds_bpermute(sel, (int)ridB);
                u32 rid = (u32)((slot < 64) ? ra : rb);
                const char* src = (const char*)(mb + (size_t)rid * MROW) + ((unsigned)(lane & 15) << 4);
                __builtin_amdgcn_global_load_lds(
                    (const __attribute__((address_space(1))) void*)src,
                    (__attribute__((address_space(3))) void*)((char*)nzbuf + i * 1024),
                    16, 0, 0);
            }
        }
        asm volatile("s_waitcnt vmcnt(0)" ::: "memory");
        __builtin_amdgcn_sched_barrier(0);
    }

    int cnt = 0;
    for (int k = 0; k < CW; ++k) {
        ull nzk;
        if (FIRST) nzk = readlane64(nzA, k);
        else       nzk = readlane64((k & 1) ? nzB : nzA, k >> 1);

        const int srcw = k >> 1;
        const ull awk = (k & 1) ? aw1 : aw0;
        ull wval = readlane64(awk, srcw);

        if (wval != 0ull) {
            const int slotbase_k = FIRST ? __builtin_amdgcn_readlane(excl, k) : 0;

            // per-lane diag word (zero rows => zero diag, no read)
            ull diag_cur = 0ull;
            if (nzk != 0ull) {
                bool mynz = (nzk >> lane) & 1ull;
                if (mynz) {
                    if (FIRST) {
                        int slot = slotbase_k + (int)__popcll(nzk & ((1ull << lane) - 1ull));
                        diag_cur = (slot < NZCAP) ? nzbuf[(size_t)slot * 32 + k]
                                                  : mb[(size_t)((k << 6) + lane) * MROW + k];
                    } else {
                        diag_cur = mb[(size_t)((k << 6) + lane) * MROW + k];
                    }
                }
            }

            // ---- lane-parallel pick resolution for word k
            const bool rowAlive = (wval >> lane) & 1ull;
            ull P;
            ull conflict = (nzk == 0ull) ? 0ull
                         : __ballot((rowAlive && ((diag_cur & wval) != 0ull)) ? 1 : 0);
            if (conflict == 0ull) {
                P = wval;
            } else {
                // transpose the 64x64 intra tile: T = "who suppresses me"
                ull Tt = diag_cur;
                {
                    ull y;
                    y = shfl_xor64(Tt, 32);
                    Tt = (lane & 32) ? ((Tt & 0xFFFFFFFF00000000ull) | ((y & 0xFFFFFFFF00000000ull) >> 32))
                                     : ((Tt & 0x00000000FFFFFFFFull) | ((y & 0x00000000FFFFFFFFull) << 32));
                    y = shfl_xor64(Tt, 16);
                    Tt = (lane & 16) ? ((Tt & 0xFFFF0000FFFF0000ull) | ((y & 0xFFFF0000FFFF0000ull) >> 16))
                                     : ((Tt & 0x0000FFFF0000FFFFull) | ((y & 0x0000FFFF0000FFFFull) << 16));
                    y = shfl_xor64(Tt, 8);
                    Tt = (lane & 8)  ? ((Tt & 0xFF00FF00FF00FF00ull) | ((y & 0xFF00FF00FF00FF00ull) >> 8))
                                     : ((Tt & 0x00FF00FF00FF00FFull) | ((y & 0x00FF00FF00FF00FFull) << 8));
                    y = shfl_xor64(Tt, 4);
                    Tt = (lane & 4)  ? ((Tt & 0xF0F0F0F0F0F0F0F0ull) | ((y & 0xF0F0F0F0F0F0F0F0ull) >> 4))
                                     : ((Tt & 0x0F0F0F0F0F0F0F0Full) | ((y & 0x0F0F0F0F0F0F0F0Full) << 4));
                    y = shfl_xor64(Tt, 2);
                    Tt = (lane & 2)  ? ((Tt & 0xCCCCCCCCCCCCCCCCull) | ((y & 0xCCCCCCCCCCCCCCCCull) >> 2))
                                     : ((Tt & 0x3333333333333333ull) | ((y & 0x3333333333333333ull) << 2));
                    y = shfl_xor64(Tt, 1);
                    Tt = (lane & 1)  ? ((Tt & 0xAAAAAAAAAAAAAAAAull) | ((y & 0xAAAAAAAAAAAAAAAAull) >> 1))
                                     : ((Tt & 0x5555555555555555ull) | ((y & 0x5555555555555555ull) << 1));
                }
                // iterative closure == sequential greedy (strictly lower-tri)
                ull A = wval;
                P = 0ull;
                while (A) {
                    const bool inA = (A >> lane) & 1ull;
                    ull D = __ballot((inA && ((Tt & A) == 0ull)) ? 1 : 0);
                    P |= D;
                    ull kill = __ballot((inA && ((Tt & D) != 0ull)) ? 1 : 0);
                    A &= ~(D | kill);
                }
            }

            // ---- ordered, PROP-capped parallel pick write
            const int total = __popcll(P);
            const int room  = PROP - cnt;
            const bool lanePicked = (P >> lane) & 1ull;
            const int myrank = __popcll(P & ((1ull << lane) - 1ull));
            if (lanePicked && myrank < room) picks[cnt + myrank] = (k << 6) + lane;
            cnt = (total >= room) ? PROP : (cnt + total);

            // ---- OR only NONZERO picked rows into alive regs
            if (cnt < PROP && nzk != 0ull) {
                ull orset = P & nzk;
                while (orset) {
                    int p = __ffsll(orset) - 1; orset &= orset - 1ull;
                    ulonglong2 v;
                    if (FIRST) {
                        int slot = slotbase_k + (int)__popcll(nzk & ((1ull << p) - 1ull));
                        if (slot < NZCAP) {
                            const ulonglong2* bv = reinterpret_cast<const ulonglong2*>(nzbuf + (size_t)slot * 32);
                            v = bv[lane & 15];
                        } else {
                            const ulonglong2* gv = reinterpret_cast<const ulonglong2*>(mb + (size_t)((k << 6) + p) * MROW);
                            v = gv[lane & 15];
                        }
                    } else {
                        const ulonglong2* gv = reinterpret_cast<const ulonglong2*>(mb + (size_t)((k << 6) + p) * MROW);
                        v = gv[min(lane, 47)];
                    }
                    aw0 &= ~v.x; aw1 &= ~v.y;
                }
            }
        }

        if (lane == (k >> 1)) { if (k & 1) aw1 = 0ull; else aw0 = 0ull; }
        if (cnt == PROP) break;
    }

    if (FIRST) {
        if (cnt != PROP) {
            if (lane == 0) atomicExch(&flags[b], 2u);   // rest pass needed
            return;
        }
        if (lane == 0) atomicExch(&flags[b], 1u);       // success
    }

    float4* ob = reinterpret_cast<float4*>(out + (size_t)b * PROP * 4);
    for (int i = lane; i < PROP; i += 64) {
        float4 v = make_float4(0.f, 0.f, 0.f, 0.f);
        if (i < cnt) v = bws_b[picks[i]];
        ob[i] = v;
    }
}

// ---------------------------------------------------------------------------
// BACK kernel: iou fast pass + scanA (+ guarded completion + scanB).
// grid (CHUNK_W, BATCH) x 1024. Block jj computes word-block jj (words
// jj..31); block 0's wave 0 runs the capped scan once its batch's 32 blocks
// ticket. flags[b]: 1 = done, 2 = cold path (complete matrix + full re-scan).
// ---------------------------------------------------------------------------
__global__ __launch_bounds__(1024, 4)
void back_kernel(const float4* __restrict__ boxes_ws, const float* __restrict__ area_ws,
                 ull* __restrict__ mat, ull* __restrict__ nzmask,
                 const ull* __restrict__ alive_ws,
                 u32* __restrict__ flags, u32* __restrict__ ticket3, u32* __restrict__ ticket4,
                 float* __restrict__ out)
{
    const int b  = blockIdx.y;
    const int jj = blockIdx.x;          // 0..31
    const int t  = threadIdx.x;

    __shared__ float4 sbox[NSLOT];                     // 96 KB
    __shared__ __align__(16) ull nzbuf[NZCAP * 32];    // 32 KB
    __shared__ float  sarea[NSLOT];                    // 24 KB
    __shared__ int    picks[PROP];                     // 4 KB
    __shared__ u32    nzrows[NZCAP];                   // 512 B
    __shared__ u32    s_flag;

    const float4* bws_b = boxes_ws + (size_t)b * NSLOT;
    const float*  aws_b = area_ws  + (size_t)b * NSLOT;
    ull* mat_b = mat    + (size_t)b * PRE_NMS * MROW;
    ull* nzm_b = nzmask + (size_t)b * NW;

    // ---- phase I: fast word-block jj (words jj..CHUNK_W-1)
    iou_block(bws_b, aws_b, mat_b, nzm_b, jj, jj, CHUNK_W, sbox, sarea);
    fence_release_agent();                 // publish mat rows
    if (t == 0) atomicAdd(&ticket3[b], 1u);

    // ---- phase S: scanA on block 0, wave 0 (barrier-free)
    if (jj == 0 && t < 64) {
        if (t == 0) {
            while (atomicAdd(&ticket3[b], 0u) < (u32)CHUNK_W) __builtin_amdgcn_s_sleep(8);
        }
        fence_acquire_agent();             // see all fast-pass mat rows
        scan_wave<true>(b, t, bws_b, alive_ws, mat_b, nzm_b, out, flags,
                        picks, nzrows, nzbuf);
    }

    // ---- phase W: wait for scanA verdict
    if (t == 0) {
        u32 f;
        while ((f = atomicAdd(&flags[b], 0u)) == 0u) __builtin_amdgcn_s_sleep(8);
        s_flag = f;
    }
    __syncthreads();
    if (s_flag == 1u) return;              // expected path

    // ---- cold path: complete matrix (rows 0..2047 words 32.., rows 2048+ all)
    for (int j = jj; j < NW; j += CHUNK_W)
        iou_block(bws_b, aws_b, mat_b, nzm_b, j, max(j, CHUNK_W), NW, sbox, sarea);
    fence_release_agent();
    if (t == 0) atomicAdd(&ticket4[b], 1u);

    if (jj == 0 && t < 64) {
        if (t == 0) {
            while (atomicAdd(&ticket4[b], 0u) < (u32)CHUNK_W) __builtin_amdgcn_s_sleep(8);
        }
        fence_acquire_agent();
        scan_wave<false>(b, t, bws_b, alive_ws, mat_b, nzm_b, out, flags,
                         picks, nzrows, nzbuf);
    }
}

// ---------------------------------------------------------------------------
// Fallback: round-1 monolithic kernel (used if ws too small). Verified exact.
// ---------------------------------------------------------------------------
__device__ __forceinline__ void hist_add_f(unsigned int* hist, unsigned int bin, bool valid) {
    const int lane = threadIdx.x & 63;
    ull todo = __ballot(valid ? 1 : 0);
    #pragma unroll
    for (int it = 0; it < 3; ++it) {
        if (!todo) return;
        int leader = __ffsll(todo) - 1;
        unsigned int lbin = __shfl(bin, leader);
        ull grp = __ballot((valid && (bin == lbin)) ? 1 : 0);
        if (lane == leader) atomicAdd(&hist[lbin], (unsigned int)__popcll(grp));
        todo &= ~grp;
    }
    if ((todo >> lane) & 1ull) atomicAdd(&hist[bin], 1u);
}

__global__ __launch_bounds__(1024)
void proposal_fallback(const float* __restrict__ rpn_probs,
                       const float* __restrict__ rpn_bbox,
                       const float* __restrict__ anchors,
                       float* __restrict__ out)
{
    const int b    = blockIdx.x;
    const int t    = threadIdx.x;
    const int lane = t & 63;
    const int wv   = t >> 6;

    const float2* __restrict__ probs2 = reinterpret_cast<const float2*>(rpn_probs + (size_t)b * NANCH * 2);
    const float4* __restrict__ bbox4  = reinterpret_cast<const float4*>(rpn_bbox  + (size_t)b * NANCH * 4);
    const float4* __restrict__ anc4   = reinterpret_cast<const float4*>(anchors   + (size_t)b * NANCH * 4);
    float* __restrict__ outb = out + (size_t)b * PROP * 4;

    __shared__ __align__(16) char s_big[NSLOT * 16];
    __shared__ ull          s_alive[96];
    __shared__ unsigned int s_hist[256];
    __shared__ unsigned int s_pref;
    __shared__ unsigned int s_targ;
    __shared__ unsigned int s_cnt;

    ull*    sel   = reinterpret_cast<ull*>(s_big);
    float4* boxes = reinterpret_cast<float4*>(s_big);

    const int ITER = (NANCH + 1023) >> 10;

    if (t == 0) { s_pref = 0u; s_targ = PRE_NMS; s_cnt = 0u; }

    for (int p = 0; p < 4; ++p) {
        if (t < 256) s_hist[t] = 0u;
        __syncthreads();
        const unsigned int pref  = s_pref;
        const int          shift = 8 * (3 - p);
        const unsigned int pmask = (p == 0) ? 0u : (0xFFFFFFFFu << (shift + 8));
        for (int i = 0; i < ITER; ++i) {
            int  n     = (i << 10) + t;
            bool valid = (n < NANCH);
            unsigned int key = 0u;
            if (valid) key = __float_as_uint(probs2[n].y);
            bool match = valid && ((key & pmask) == (pref & pmask));
            hist_add_f(s_hist, (key >> shift) & 0xFFu, match);
        }
        __syncthreads();
        if (t == 0) {
            unsigned int target = s_targ;
            unsigned int acc = 0u;
            int v = 255;
            for (; v >= 0; --v) {
                unsigned int h = s_hist[v];
                if (acc + h >= target) break;
                acc += h;
            }
            if (v < 0) v = 0;
            s_pref = pref | ((unsigned int)v << shift);
            s_targ = target - acc;
        }
        __syncthreads();
    }

    const unsigned int T = s_pref;
    __syncthreads();

    for (int i = 0; i < ITER; ++i) {
        int  n     = (i << 10) + t;
        bool valid = (n < NANCH);
        unsigned int key = 0u;
        if (valid) key = __float_as_uint(probs2[n].y);
        bool selp = valid && (key >= T);
        ull  m    = __ballot(selp ? 1 : 0);
        if (m) {
            int leader = __ffsll(m) - 1;
            unsigned int base = 0u;
            if (lane == leader) base = atomicAdd(&s_cnt, (unsigned int)__popcll(m));
            base = __shfl(base, leader);
            if (selp) {
                unsigned int off = base + (unsigned int)__popcll(m & ((1ull << lane) - 1ull));
                if (off < SORTN) sel[off] = ((ull)(~key) << 32) | (ull)(unsigned int)n;
            }
        }
    }
    __syncthreads();
    const unsigned int C = s_cnt;
    for (int s = (int)C + t; s < SORTN; s += 1024) sel[s] = ~0ull;
    __syncthreads();

    for (unsigned int k = 2; k <= SORTN; k <<= 1) {
        for (unsigned int j = k >> 1; j > 0; j >>= 1) {
            #pragma unroll
            for (int r = 0; r < SORTN / 1024; ++r) {
                int i = (r << 10) + t;
                int l = i ^ (int)j;
                if (l > i) {
                    ull a  = sel[i];
                    ull bq = sel[l];
                    bool up = ((i & (int)k) == 0);
                    if ((a > bq) == up) { sel[i] = bq; sel[l] = a; }
                }
            }
            __syncthreads();
        }
    }

    ull ss[6];
    #pragma unroll
    for (int e = 0; e < 6; ++e) ss[e] = sel[(e << 10) + t];
    __syncthreads();

    float4 rbox[6];
    float  rarea[6];
    #pragma unroll
    for (int e = 0; e < 6; ++e) {
        int s = (e << 10) + t;
        float4 bx = make_float4(0.f, 0.f, 0.f, 0.f);
        bool ok = false;
        if (s < PRE_NMS) {
            unsigned int key = ~(unsigned int)(ss[e] >> 32);
            unsigned int n   = (unsigned int)(ss[e] & 0xFFFFFFFFull);
            float4 a = anc4[n];
            float4 d = bbox4[n];
            float dy = d.x * 0.1f, dx = d.y * 0.1f, dh = d.z * 0.2f, dw = d.w * 0.2f;
            float h  = a.z - a.x;
            float w  = a.w - a.y;
            float cy = a.x + 0.5f * h;
            float cx = a.y + 0.5f * w;
            cy = cy + dy * h;
            cx = cx + dx * w;
            h  = h * expf(dh);
            w  = w * expf(dw);
            float y1 = cy - 0.5f * h;
            float x1 = cx - 0.5f * w;
            float y2 = y1 + h;
            float x2 = x1 + w;
            y1 = fminf(fmaxf(y1, 0.f), 1.f);
            x1 = fminf(fmaxf(x1, 0.f), 1.f);
            y2 = fminf(fmaxf(y2, 0.f), 1.f);
            x2 = fminf(fmaxf(x2, 0.f), 1.f);
            bx = make_float4(y1, x1, y2, x2);
            ok = (key >= SCORE_THRES_BITS);
        }
        rbox[e]  = bx;
        rarea[e] = (bx.z - bx.x) * (bx.w - bx.y);
        boxes[s] = bx;
        ull am = __ballot(ok ? 1 : 0);
        if (lane == 0) s_alive[wv + (e << 4)] = am;
    }

    int emitted = 0;
    for (;;) {
        __syncthreads();
        if (emitted == PROP) break;
        ull w0 = s_alive[lane];
        ull w1 = (lane < 32) ? s_alive[64 + lane] : 0ull;
        ull nz0 = __ballot(w0 != 0ull ? 1 : 0);
        ull nz1 = __ballot(w1 != 0ull ? 1 : 0);
        int pick = -1;
        if (nz0) {
            int wd = __ffsll(nz0) - 1;
            ull wvv = __shfl(w0, wd);
            pick = (wd << 6) + __ffsll(wvv) - 1;
        } else if (nz1) {
            int wd = __ffsll(nz1) - 1;
            ull wvv = __shfl(w1, wd);
            pick = ((wd + 64) << 6) + __ffsll(wvv) - 1;
        }
        if (pick < 0) break;
        __syncthreads();

        if (t < 4) outb[(emitted << 2) + t] = reinterpret_cast<const float*>(s_big)[(pick << 2) + t];

        float4 p = boxes[pick];
        float parea = (p.z - p.x) * (p.w - p.y);
        #pragma unroll
        for (int e = 0; e < 6; ++e) {
            float4 bb  = rbox[e];
            float yy1 = fmaxf(p.x, bb.x);
            float xx1 = fmaxf(p.y, bb.y);
            float yy2 = fminf(p.z, bb.z);
            float xx2 = fminf(p.w, bb.w);
            float ih  = fmaxf(yy2 - yy1, 0.f);
            float iw  = fmaxf(xx2 - xx1, 0.f);
            float inter = ih * iw;
            float denom = ((parea + rarea[e]) - inter) + EPS_F;
            bool  sup   = ((double)inter > M_D * (double)denom);
            ull m = __ballot(sup ? 1 : 0);
            int word = wv + (e << 4);
            if (word == (pick >> 6)) m |= (1ull << (pick & 63));
            if (lane == 0) s_alive[word] &= ~m;
        }
        ++emitted;
    }

    for (int i = (emitted << 2) + t; i < PROP * 4; i += 1024) outb[i] = 0.f;
}

extern "C" void kernel_launch(void* const* d_in, const int* in_sizes, int n_in,
                              void* d_out, int out_size, void* d_ws, size_t ws_size,
                              hipStream_t stream) {
    const float* rpn_probs = (const float*)d_in[0];
    const float* rpn_bbox  = (const float*)d_in[1];
    const float* anchors   = (const float*)d_in[2];
    float* out = (float*)d_out;

    // ws layout:
    //   [0)        boxes   8*6144*16 = 786432
    //   [786432)   areas   8*6144*4  = 196608   -> ends 983040
    //   [983040)   ZERO region (one memset to MAT_OFF):
    //       alive   8*96*8 = 6144   @983040
    //       Tc      32 B            @989184
    //       done    32 B            @989440
    //       cntp    8*64*4 = 2048   @989696
    //       ghist   8*256*4 = 8192  @991744   -> ends 999936
    //       flags   8*4 = 32 B      @999936
    //       binbase 8*132*4 = 4224  @1000448
    //       bincnt  8*132*4 = 4224  @1004672
    //       nzmask  8*94*8 = 6016   @1008896  -> ends 1014912
    //       done2   32 B            @1014912
    //       ticket3 32 B            @1015424
    //       ticket4 32 B            @1015936
    //   [1MiB)     mat (selbuf aliased at its head, consumed before mat write)
    const size_t BOX_OFF   = 0;
    const size_t AREA_OFF  = 786432;
    const size_t ZERO_OFF  = 983040;
    const size_t ALIVE_OFF = 983040;
    const size_t TC_OFF    = 989184;
    const size_t DONE_OFF  = 989440;
    const size_t CNT_OFF   = 989696;
    const size_t GHIST_OFF = 991744;
    const size_t FLAG_OFF  = 999936;
    const size_t BINB_OFF  = 1000448;
    const size_t BINC_OFF  = 1004672;
    const size_t NZ_OFF    = 1008896;
    const size_t DONE2_OFF = 1014912;
    const size_t TK3_OFF   = 1015424;
    const size_t TK4_OFF   = 1015936;
    const size_t MAT_OFF   = 1u << 20;
    const size_t SELB_OFF  = MAT_OFF;
    const size_t WS_NEED   = MAT_OFF + (size_t)BATCH * PRE_NMS * MROW * 8;     // ~37.9 MB

    if (d_ws != nullptr && ws_size >= WS_NEED) {
        char* ws = (char*)d_ws;
        float4* boxes_ws = (float4*)(ws + BOX_OFF);
        float*  area_ws  = (float*)(ws + AREA_OFF);
        ull*    alive_ws = (ull*)(ws + ALIVE_OFF);
        u32*    Tc       = (u32*)(ws + TC_OFF);
        u32*    done     = (u32*)(ws + DONE_OFF);
        u32*    cntp     = (u32*)(ws + CNT_OFF);
        u32*    ghist    = (u32*)(ws + GHIST_OFF);
        u32*    flags    = (u32*)(ws + FLAG_OFF);
        u32*    binbase  = (u32*)(ws + BINB_OFF);
        u32*    bincnt   = (u32*)(ws + BINC_OFF);
        ull*    nzmask   = (ull*)(ws + NZ_OFF);
        u32*    done2    = (u32*)(ws + DONE2_OFF);
        u32*    ticket3  = (u32*)(ws + TK3_OFF);
        u32*    ticket4  = (u32*)(ws + TK4_OFF);
        ull*    selbuf   = (ull*)(ws + SELB_OFF);
        ull*    mat      = (ull*)(ws + MAT_OFF);

        hipMemsetAsync(ws + ZERO_OFF, 0, MAT_OFF - ZERO_OFF, stream);  // alive..tickets
        hipLaunchKernelGGL(front_kernel, dim3(CBLK, BATCH), dim3(256), 0, stream,
                           rpn_probs, rpn_bbox, anchors,
                           ghist, done, Tc, binbase, cntp, bincnt, selbuf, done2,
                           boxes_ws, area_ws, alive_ws);
        hipLaunchKernelGGL(back_kernel, dim3(CHUNK_W, BATCH), dim3(1024), 0, stream,
                           boxes_ws, area_ws, mat, nzmask, alive_ws,
                           flags, ticket3, ticket4, out);
    } else {
        hipLaunchKernelGGL(proposal_fallback, dim3(BATCH), dim3(1024), 0, stream,
                           rpn_probs, rpn_bbox, anchors, out);
    }
}

// Round 9
// 198.407 us; speedup vs baseline: 1.7210x; 1.7210x over previous
//
#include <hip/hip_runtime.h>
#include <cstdint>
#include <cstddef>

#pragma clang fp contract(off)

#define BATCH    8
#define NANCH    261888
#define PRE_NMS  6000
#define PROP     1000
#define SORTN    8192
#define NSLOT    6144          /* 6 * 1024 */
#define MROW     96            /* u64 words per suppression row (94 used + 2 pad) */
#define NW       94            /* suppression words per batch (6000/64 rounded up) */
#define CHUNK_W  32            /* words computed+scanned in the fast first pass */
#define NZCAP    128           /* LDS-stashed nonzero rows (capped scan) */
#define NPAIR    130944        /* NANCH / 2 */
#define CBLK     64            /* blocks per batch for hist/compact */
#define CPAIR    2046          /* NPAIR / CBLK */
#define KCAP     1024          /* compact LDS staging capacity */
#define SCORE_THRES_BITS 0x3F000000u   /* bits of 0.5f */
#define EPS_F    1e-8f
/* midpoint between pred(0.7f) and 0.7f = 23488101 * 2^-25, exact in double.
   RN(inter/denom) >= 0.7f  <=>  inter > M_D * denom  (exact: 25b x 24b product;
   tie rounds to even = pred(0.7f), so strict > is correct). */
#define M_D      0.6999999582767486572265625

typedef unsigned long long ull;
typedef unsigned int u32;

// ---------------------------------------------------------------------------
// R18: REVERT of R17's full fusion (hot-path spin+fence sync cost ~10x more
// than the launch gaps it removed: front 42us -> 140us). Structure is R16's
// split pipeline, with:
//   (1) hist/compact widened to 512-thread blocks (R16 counters: VALUBusy
//       0.6%, Occupancy 15% -> latency-bound, needs more waves in flight);
//   (2) the two guarded tail launches merged into ONE rest_kernel whose hot
//       path is a single flag load + return (inter-kernel visibility is
//       guaranteed at dispatch boundaries; spin/fence only on the never-
//       taken cold path). 9 -> 7 dispatches.
// ---------------------------------------------------------------------------

__device__ __forceinline__ void fence_release_agent()
{
    __builtin_amdgcn_fence(__ATOMIC_RELEASE, "agent");
}
__device__ __forceinline__ void fence_acquire_agent()
{
    __builtin_amdgcn_fence(__ATOMIC_ACQUIRE, "agent");
}

// ---------------------------------------------------------------------------
// Kernel A: fused hist + findT + binbase. 512 threads (R18: was 256).
// grid (CBLK, BATCH) x 512.
// ---------------------------------------------------------------------------
__global__ __launch_bounds__(512)
void hist_kernel(const float* __restrict__ rpn_probs, u32* __restrict__ ghist,
                 u32* __restrict__ done, u32* __restrict__ Tc,
                 u32* __restrict__ binbase, u32* __restrict__ cntp)
{
    __shared__ u32 h[132];
    __shared__ u32 s_old;
    const int t = threadIdx.x;
    const int b = blockIdx.y;
    if (t < 132) h[t] = 0u;
    __syncthreads();

    const float4* p4 = reinterpret_cast<const float4*>(rpn_probs + (size_t)b * NANCH * 2);
    const int p0 = blockIdx.x * CPAIR;
    for (int i = t; i < CPAIR; i += 512) {
        float4 v = p4[p0 + i];                 // scores of anchors 2p, 2p+1 in .y/.w
        u32 k0 = __float_as_uint(v.y);
        u32 k1 = __float_as_uint(v.w);
        if (k0 >= 0x3F000000u) atomicAdd(&h[min((k0 >> 16) - 0x3F00u, 128u)], 1u);
        if (k1 >= 0x3F000000u) atomicAdd(&h[min((k1 >> 16) - 0x3F00u, 128u)], 1u);
    }
    __syncthreads();
    if (t < 129 && h[t]) atomicAdd(&ghist[(b << 8) + t], h[t]);

    // order: this block's ghist atomics performed before the done++ ticket
    // (atomics complete at the coherent point when vmcnt drains; no L2
    // maintenance needed, unlike __threadfence's buffer_inv — R16 lesson).
    asm volatile("s_waitcnt vmcnt(0)" ::: "memory");
    if (t == 0) s_old = atomicAdd(&done[b], 1u);
    __syncthreads();
    if (s_old == CBLK - 1) {
        // last block for this batch: all ghist atomics globally performed
        if (t < 129) h[t] = atomicAdd(&ghist[(b << 8) + t], 0u);   // coherent read
        __syncthreads();
        if (t == 0) {
            u32* bb = binbase + b * 132;
            u32 run = 0; int binT = -1; u32 Cv = 0;
            for (int i = 128; i >= 0; --i) {
                bb[i] = run;                    // # keys in bins strictly above i
                run += h[i];
                if (binT < 0 && run >= PRE_NMS) { binT = i; Cv = run; }
            }
            u32 T;
            if (binT < 0)         { T = 0x3F000000u; Cv = run; }  // unreachable
            else if (binT == 128)   T = 0x3F800000u;
            else                    T = 0x3F000000u + ((u32)binT << 16);
            Tc[b] = T;
            cntp[b << 6] = Cv;
        }
    }
}

// ---------------------------------------------------------------------------
// Kernel C: bucketed compact with two-level atomic aggregation (R15), 512
// threads (R18). grid (CBLK, BATCH) x 512.
// ---------------------------------------------------------------------------
__global__ __launch_bounds__(512)
void compact_kernel(const float* __restrict__ rpn_probs,
                    const u32* __restrict__ Tc,
                    const u32* __restrict__ binbase,
                    u32* __restrict__ bincnt,
                    ull* __restrict__ selbuf)
{
    __shared__ ull kbuf[KCAP];
    __shared__ u32 s_n;
    __shared__ u32 s_hist[132];
    __shared__ u32 s_base[132];
    const int t    = threadIdx.x;
    const int lane = t & 63;
    const int b    = blockIdx.y;
    const u32 T = Tc[b];
    const u32* bb = binbase + b * 132;
    u32* bc = bincnt + b * 132;
    if (t == 0) s_n = 0u;
    if (t < 132) s_hist[t] = 0u;
    __syncthreads();

    const float4* p4 = reinterpret_cast<const float4*>(rpn_probs + (size_t)b * NANCH * 2);
    ull* sb = selbuf + (size_t)b * SORTN;
    const int p0 = blockIdx.x * CPAIR;

    // ---- phase 1: stage selected keys in LDS (one LDS atomic per wave-group)
    for (int i = t; i < CPAIR; i += 512) {
        float4 v = p4[p0 + i];
        const int n0 = (p0 + i) << 1;
        #pragma unroll
        for (int e = 0; e < 2; ++e) {
            u32 k = __float_as_uint(e ? v.w : v.y);
            bool s0 = (k >= T);
            ull m = __ballot(s0 ? 1 : 0);
            if (!m) continue;                                  // wave-uniform
            int ldr = __ffsll(m) - 1;
            u32 base = 0;
            if (lane == ldr) base = atomicAdd(&s_n, (u32)__popcll(m));
            base = __shfl(base, ldr);
            u32 off = base + (u32)__popcll(m & ((1ull << lane) - 1ull));
            if (s0) {
                ull pk = ((ull)(~k) << 32) | (ull)(u32)(n0 + e);
                if (off < KCAP) {
                    kbuf[off] = pk;
                } else {
                    // exact spill (unreachable at ~100 staged/block)
                    u32 bin = min((k >> 16) - 0x3F00u, 128u);
                    u32 pos = bb[bin] + atomicAdd(&bc[bin], 1u);
                    if (pos < SORTN) sb[pos] = pk;
                }
            }
        }
    }
    __syncthreads();
    const u32 nn = min(s_n, (u32)KCAP);

    // ---- phase 2: per-block bin histogram
    for (u32 j = t; j < nn; j += 512) {
        u32 k = ~(u32)(kbuf[j] >> 32);
        atomicAdd(&s_hist[min((k >> 16) - 0x3F00u, 128u)], 1u);
    }
    __syncthreads();

    // ---- phase 3: reserve this block's range in each active bin
    if (t < 132 && s_hist[t]) s_base[t] = atomicAdd(&bc[t], s_hist[t]);
    __syncthreads();
    if (t < 132) s_hist[t] = 0u;      // reuse as local position counters
    __syncthreads();

    // ---- phase 4: scatter
    for (u32 j = t; j < nn; j += 512) {
        ull kv = kbuf[j];
        u32 k = ~(u32)(kv >> 32);
        u32 bin = min((k >> 16) - 0x3F00u, 128u);
        u32 local = atomicAdd(&s_hist[bin], 1u);
        u32 pos = bb[bin] + s_base[bin] + local;
        if (pos < SORTN) sb[pos] = kv;
    }
}

// ---------------------------------------------------------------------------
// Kernel D: bucketed rank + decode + scatter (R13). grid (32, BATCH) x 256.
// ---------------------------------------------------------------------------
__global__ __launch_bounds__(256)
void rank_decode_kernel(const float* __restrict__ rpn_bbox,
                        const float* __restrict__ anchors,
                        const ull* __restrict__ selbuf,
                        const u32* __restrict__ cntp,
                        const u32* __restrict__ binbase,
                        const u32* __restrict__ ghist,
                        float4* __restrict__ boxes_ws,
                        float* __restrict__ area_ws,
                        ull* __restrict__ alive_ws)
{
    const int t = threadIdx.x;
    const int b = blockIdx.y;
    const u32 C = min(cntp[b << 6], (u32)SORTN);
    const ull* sb = selbuf + (size_t)b * SORTN;

    const int i = (blockIdx.x << 8) + t;
    if (i >= (int)C) return;

    const ull mykey = sb[i];
    const u32 key = ~(u32)(mykey >> 32);
    const u32 n   = (u32)(mykey & 0xFFFFFFFFull);
    const u32 bin = min((key >> 16) - 0x3F00u, 128u);
    const u32 lo  = binbase[b * 132 + bin];
    const u32 cb  = min(ghist[(b << 8) + bin], (u32)SORTN - lo);  // bin size (clamped)

    const ull* base = sb + lo;
    int local = 0;
    u32 j = 0;
    for (; j + 8 <= cb; j += 8) {
        #pragma unroll
        for (int u = 0; u < 8; ++u) local += (base[j + u] < mykey) ? 1 : 0;
    }
    for (; j < cb; ++j) local += (base[j] < mykey) ? 1 : 0;
    const int rank = (int)lo + local;

    if (rank < PRE_NMS) {
        const float4* bbox4 = reinterpret_cast<const float4*>(rpn_bbox + (size_t)b * NANCH * 4);
        const float4* anc4  = reinterpret_cast<const float4*>(anchors  + (size_t)b * NANCH * 4);
        float4 a = anc4[n];
        float4 d = bbox4[n];
        float dy = d.x * 0.1f, dx = d.y * 0.1f, dh = d.z * 0.2f, dw = d.w * 0.2f;
        float h  = a.z - a.x;
        float w  = a.w - a.y;
        float cy = a.x + 0.5f * h;
        float cx = a.y + 0.5f * w;
        cy = cy + dy * h;
        cx = cx + dx * w;
        h  = h * expf(dh);
        w  = w * expf(dw);
        float y1 = cy - 0.5f * h;
        float x1 = cx - 0.5f * w;
        float y2 = y1 + h;
        float x2 = x1 + w;
        y1 = fminf(fmaxf(y1, 0.f), 1.f);
        x1 = fminf(fmaxf(x1, 0.f), 1.f);
        y2 = fminf(fmaxf(y2, 0.f), 1.f);
        x2 = fminf(fmaxf(x2, 0.f), 1.f);
        boxes_ws[(size_t)b * NSLOT + rank] = make_float4(y1, x1, y2, x2);
        area_ws[(size_t)b * NSLOT + rank]  = (y2 - y1) * (x2 - x1);
        if (key >= SCORE_THRES_BITS) {
            atomicOr(&alive_ws[(size_t)b * MROW + (rank >> 6)], 1ull << (rank & 63));
        }
    }
}

// ---------------------------------------------------------------------------
// iou word-block body: stage cols, compute suppression words kbeg..kend-1 for
// the 64 rows of word-block j (16 waves x 4 rows), publish nzmask bits.
// ---------------------------------------------------------------------------
__device__ void iou_block(const float4* __restrict__ bws_b,
                          const float* __restrict__ aws_b,
                          ull* __restrict__ mat_b, ull* __restrict__ nzm_b,
                          int j, int kbeg, int kend,
                          float4* sbox, float* sarea)
{
    const int t    = threadIdx.x;
    const int lane = t & 63;
    const int wv   = t >> 6;
    const int base = j << 6;
    const int nst  = (kend << 6) - base;

    for (int i = t; i < nst; i += 1024) { sbox[i] = bws_b[base + i]; sarea[i] = aws_b[base + i]; }
    __syncthreads();

    const int r0 = base + (wv << 2);
    if (r0 < PRE_NMS) {
        float4 P[4];
        float  PA[4];
        #pragma unroll
        for (int qi = 0; qi < 4; ++qi) { P[qi] = sbox[(wv << 2) + qi]; PA[qi] = sarea[(wv << 2) + qi]; }

        ull* rowp = mat_b + (size_t)r0 * MROW;
        ull acc[4] = {0ull, 0ull, 0ull, 0ull};

        for (int k = kbeg; k < kend; ++k) {
            const int ci = ((k - j) << 6) + lane;
            const float4 qb = sbox[ci];
            const float  qa = sarea[ci];
            ull m[4];
            #pragma unroll
            for (int qi = 0; qi < 4; ++qi) {
                float yy1 = fmaxf(P[qi].x, qb.x);
                float xx1 = fmaxf(P[qi].y, qb.y);
                float yy2 = fminf(P[qi].z, qb.z);
                float xx2 = fminf(P[qi].w, qb.w);
                float inter = fmaxf(yy2 - yy1, 0.f) * fmaxf(xx2 - xx1, 0.f);
                float denom = ((PA[qi] + qa) - inter) + EPS_F;
                m[qi] = __ballot(((double)inter > M_D * (double)denom) ? 1 : 0);
            }
            if (k == j) {                       // diagonal word: mask away c <= r
                #pragma unroll
                for (int qi = 0; qi < 4; ++qi) {
                    int sh = (wv << 2) + qi;
                    ull keep = (sh == 63) ? 0ull : ((~0ull) << (sh + 1));
                    m[qi] &= keep;
                }
            }
            #pragma unroll
            for (int qi = 0; qi < 4; ++qi) acc[qi] |= m[qi];
            if (lane == 0) {
                #pragma unroll
                for (int qi = 0; qi < 4; ++qi) rowp[(size_t)qi * MROW + k] = m[qi];
            }
        }

        if (lane == 0) {
            u32 bits = 0;
            #pragma unroll
            for (int qi = 0; qi < 4; ++qi) if (acc[qi]) bits |= 1u << qi;
            if (bits) atomicOr(&nzm_b[j], (ull)bits << (wv << 2));
        }
    }
    __syncthreads();   // protect sbox for the caller's next staging
}

// ---------------------------------------------------------------------------
// Kernel E (fast pass): grid (CHUNK_W, BATCH) x 1024, words jj..CHUNK_W-1.
// ---------------------------------------------------------------------------
__global__ __launch_bounds__(1024)
void iou_chunk_kernel(const float4* __restrict__ boxes_ws,
                      const float* __restrict__ area_ws,
                      ull* __restrict__ mat,
                      ull* __restrict__ nzmask)
{
    const int b = blockIdx.y;
    __shared__ float4 sbox[NSLOT];    // 96 KB
    __shared__ float  sarea[NSLOT];   // 24 KB
    iou_block(boxes_ws + (size_t)b * NSLOT, area_ws + (size_t)b * NSLOT,
              mat + (size_t)b * PRE_NMS * MROW, nzmask + (size_t)b * NW,
              blockIdx.x, blockIdx.x, CHUNK_W, sbox, sarea);
}

// ---------------------------------------------------------------------------
// scan_wave: greedy word-walk by ONE wave (64 lanes), nzmask-driven (R14).
//   FIRST=true : capped scan (words 0..CHUNK_W-1), LDS row stash; on success
//                writes output + flags[b]=1, else flags[b]=2.
//   FIRST=false: full scan (words 0..NW-1), on-demand global row reads;
//                always writes output.
// ---------------------------------------------------------------------------
__device__ __forceinline__ ull shfl_xor64(ull x, int s)
{
    return (ull)__shfl_xor((long long)x, s, 64);
}

__device__ __forceinline__ ull readlane64(ull x, int l)
{
    u32 lo = (u32)__builtin_amdgcn_readlane((int)(u32)x, l);
    u32 hi = (u32)__builtin_amdgcn_readlane((int)(u32)(x >> 32), l);
    return ((ull)hi << 32) | (ull)lo;
}

template<bool FIRST>
__device__ void scan_wave(int b, int lane,
                          const float4* __restrict__ bws_b,
                          const ull* __restrict__ alive_ws,
                          const ull* __restrict__ mb,
                          const ull* __restrict__ nzm,
                          float* __restrict__ out,
                          u32* __restrict__ flags,
                          int* picks, u32* nzrows, ull* nzbuf)
{
    const int CW = FIRST ? CHUNK_W : NW;

    // lane l (<48) holds alive words 2l, 2l+1 (words 94,95 zero by construction)
    ull aw0 = 0, aw1 = 0;
    if (lane < 48) {
        const ull* aw = alive_ws + (size_t)b * MROW + 2 * lane;
        aw0 = aw[0]; aw1 = aw[1];
    }

    ull nzA = 0, nzB = 0;
    if (FIRST) { if (lane < CHUNK_W) nzA = nzm[lane]; }
    else       { if (lane < 47)      { nzA = nzm[2 * lane]; nzB = nzm[2 * lane + 1]; } }

    int excl = 0, NZ = 0;
    if (FIRST) {
        // exclusive prefix of per-word nz popcounts over lanes 0..31
        int c = (int)__popcll(nzA);
        int incl = c;
        for (int s = 1; s < 32; s <<= 1) {
            int y = __shfl_up(incl, s, 64);
            if (lane >= s) incl += y;
        }
        excl = incl - c;
        NZ = __builtin_amdgcn_readlane(incl, 31);

        // build compacted nonzero-row list (slots < NZCAP)
        {
            ull m = nzA; int r = excl;
            while (m) {
                int p = __ffsll(m) - 1; m &= m - 1ull;
                if (r < NZCAP) nzrows[r] = (u32)((lane << 6) + p);
                ++r;
            }
        }
        // stash nonzero rows (words 0..31 = 256 B each) into LDS; 4 rows/inst
        const int NP = min(NZ, NZCAP);
        if (NP > 0) {
            u32 ridA = nzrows[lane];
            u32 ridB = nzrows[64 + lane];
            const int ninst = (NP + 3) >> 2;
            for (int i = 0; i < ninst; ++i) {
                int slot = 4 * i + (lane >> 4);
                if (slot >= NP) slot = NP - 1;
                int sel = (slot & 63) << 2;
                int ra = __builtin_amdgcn_ds_bpermute(sel, (int)ridA);
                int rb = __builtin_amdgcn_ds_bpermute(sel, (int)ridB);
                u32 rid = (u32)((slot < 64) ? ra : rb);
                const char* src = (const char*)(mb + (size_t)rid * MROW) + ((unsigned)(lane & 15) << 4);
                __builtin_amdgcn_global_load_lds(
                    (const __attribute__((address_space(1))) void*)src,
                    (__attribute__((address_space(3))) void*)((char*)nzbuf + i * 1024),
                    16, 0, 0);
            }
        }
        asm volatile("s_waitcnt vmcnt(0)" ::: "memory");
        __builtin_amdgcn_sched_barrier(0);
    }

    int cnt = 0;
    for (int k = 0; k < CW; ++k) {
        ull nzk;
        if (FIRST) nzk = readlane64(nzA, k);
        else       nzk = readlane64((k & 1) ? nzB : nzA, k >> 1);

        const int srcw = k >> 1;
        const ull awk = (k & 1) ? aw1 : aw0;
        ull wval = readlane64(awk, srcw);

        if (wval != 0ull) {
            const int slotbase_k = FIRST ? __builtin_amdgcn_readlane(excl, k) : 0;

            // per-lane diag word (zero rows => zero diag, no read)
            ull diag_cur = 0ull;
            if (nzk != 0ull) {
                bool mynz = (nzk >> lane) & 1ull;
                if (mynz) {
                    if (FIRST) {
                        int slot = slotbase_k + (int)__popcll(nzk & ((1ull << lane) - 1ull));
                        diag_cur = (slot < NZCAP) ? nzbuf[(size_t)slot * 32 + k]
                                                  : mb[(size_t)((k << 6) + lane) * MROW + k];
                    } else {
                        diag_cur = mb[(size_t)((k << 6) + lane) * MROW + k];
                    }
                }
            }

            // ---- lane-parallel pick resolution for word k
            const bool rowAlive = (wval >> lane) & 1ull;
            ull P;
            ull conflict = (nzk == 0ull) ? 0ull
                         : __ballot((rowAlive && ((diag_cur & wval) != 0ull)) ? 1 : 0);
            if (conflict == 0ull) {
                P = wval;
            } else {
                // transpose the 64x64 intra tile: T = "who suppresses me"
                ull Tt = diag_cur;
                {
                    ull y;
                    y = shfl_xor64(Tt, 32);
                    Tt = (lane & 32) ? ((Tt & 0xFFFFFFFF00000000ull) | ((y & 0xFFFFFFFF00000000ull) >> 32))
                                     : ((Tt & 0x00000000FFFFFFFFull) | ((y & 0x00000000FFFFFFFFull) << 32));
                    y = shfl_xor64(Tt, 16);
                    Tt = (lane & 16) ? ((Tt & 0xFFFF0000FFFF0000ull) | ((y & 0xFFFF0000FFFF0000ull) >> 16))
                                     : ((Tt & 0x0000FFFF0000FFFFull) | ((y & 0x0000FFFF0000FFFFull) << 16));
                    y = shfl_xor64(Tt, 8);
                    Tt = (lane & 8)  ? ((Tt & 0xFF00FF00FF00FF00ull) | ((y & 0xFF00FF00FF00FF00ull) >> 8))
                                     : ((Tt & 0x00FF00FF00FF00FFull) | ((y & 0x00FF00FF00FF00FFull) << 8));
                    y = shfl_xor64(Tt, 4);
                    Tt = (lane & 4)  ? ((Tt & 0xF0F0F0F0F0F0F0F0ull) | ((y & 0xF0F0F0F0F0F0F0F0ull) >> 4))
                                     : ((Tt & 0x0F0F0F0F0F0F0F0Full) | ((y & 0x0F0F0F0F0F0F0F0Full) << 4));
                    y = shfl_xor64(Tt, 2);
                    Tt = (lane & 2)  ? ((Tt & 0xCCCCCCCCCCCCCCCCull) | ((y & 0xCCCCCCCCCCCCCCCCull) >> 2))
                                     : ((Tt & 0x3333333333333333ull) | ((y & 0x3333333333333333ull) << 2));
                    y = shfl_xor64(Tt, 1);
                    Tt = (lane & 1)  ? ((Tt & 0xAAAAAAAAAAAAAAAAull) | ((y & 0xAAAAAAAAAAAAAAAAull) >> 1))
                                     : ((Tt & 0x5555555555555555ull) | ((y & 0x5555555555555555ull) << 1));
                }
                // iterative closure == sequential greedy (strictly lower-tri)
                ull A = wval;
                P = 0ull;
                while (A) {
                    const bool inA = (A >> lane) & 1ull;
                    ull D = __ballot((inA && ((Tt & A) == 0ull)) ? 1 : 0);
                    P |= D;
                    ull kill = __ballot((inA && ((Tt & D) != 0ull)) ? 1 : 0);
                    A &= ~(D | kill);
                }
            }

            // ---- ordered, PROP-capped parallel pick write
            const int total = __popcll(P);
            const int room  = PROP - cnt;
            const bool lanePicked = (P >> lane) & 1ull;
            const int myrank = __popcll(P & ((1ull << lane) - 1ull));
            if (lanePicked && myrank < room) picks[cnt + myrank] = (k << 6) + lane;
            cnt = (total >= room) ? PROP : (cnt + total);

            // ---- OR only NONZERO picked rows into alive regs
            if (cnt < PROP && nzk != 0ull) {
                ull orset = P & nzk;
                while (orset) {
                    int p = __ffsll(orset) - 1; orset &= orset - 1ull;
                    ulonglong2 v;
                    if (FIRST) {
                        int slot = slotbase_k + (int)__popcll(nzk & ((1ull << p) - 1ull));
                        if (slot < NZCAP) {
                            const ulonglong2* bv = reinterpret_cast<const ulonglong2*>(nzbuf + (size_t)slot * 32);
                            v = bv[lane & 15];
                        } else {
                            const ulonglong2* gv = reinterpret_cast<const ulonglong2*>(mb + (size_t)((k << 6) + p) * MROW);
                            v = gv[lane & 15];
                        }
                    } else {
                        const ulonglong2* gv = reinterpret_cast<const ulonglong2*>(mb + (size_t)((k << 6) + p) * MROW);
                        v = gv[min(lane, 47)];
                    }
                    aw0 &= ~v.x; aw1 &= ~v.y;
                }
            }
        }

        if (lane == (k >> 1)) { if (k & 1) aw1 = 0ull; else aw0 = 0ull; }
        if (cnt == PROP) break;
    }

    if (FIRST) {
        if (cnt != PROP) {
            if (lane == 0) atomicExch(&flags[b], 2u);   // rest pass needed
            return;
        }
        if (lane == 0) atomicExch(&flags[b], 1u);       // success
    }

    float4* ob = reinterpret_cast<float4*>(out + (size_t)b * PROP * 4);
    for (int i = lane; i < PROP; i += 64) {
        float4 v = make_float4(0.f, 0.f, 0.f, 0.f);
        if (i < cnt) v = bws_b[picks[i]];
        ob[i] = v;
    }
}

// ---------------------------------------------------------------------------
// Kernel F: capped scan (hot path). grid (BATCH) x 64.
// ---------------------------------------------------------------------------
__global__ __launch_bounds__(64)
__attribute__((amdgpu_waves_per_eu(1, 1)))
void scanA_kernel(const float4* __restrict__ boxes_ws,
                  const ull* __restrict__ alive_ws,
                  const ull* __restrict__ mat,
                  const ull* __restrict__ nzmask,
                  float* __restrict__ out,
                  u32* __restrict__ flags)
{
    const int b = blockIdx.x;
    __shared__ int picks[PROP];                        // 4 KB
    __shared__ u32 nzrows[NZCAP];                      // 512 B
    __shared__ __align__(16) ull nzbuf[NZCAP * 32];    // 32 KB
    scan_wave<true>(b, threadIdx.x, boxes_ws + (size_t)b * NSLOT, alive_ws,
                    mat + (size_t)b * PRE_NMS * MROW, nzmask + (size_t)b * NW,
                    out, flags, picks, nzrows, nzbuf);
}

// ---------------------------------------------------------------------------
// Kernel G (R18): merged guarded completion — replaces the R16 pair
// {guarded iou_chunk, guarded scanB}. Hot path: one flag load + return
// (flags written by the PREVIOUS dispatch; inter-kernel visibility is
// guaranteed at dispatch boundaries, no fence). Cold path (never taken on
// this data, exactness-preserving): complete the matrix, ticket, then
// block (0,b)'s wave 0 runs the full re-scan. grid (NW, BATCH) x 1024.
// ---------------------------------------------------------------------------
__global__ __launch_bounds__(1024)
void rest_kernel(const float4* __restrict__ boxes_ws,
                 const float* __restrict__ area_ws,
                 ull* __restrict__ mat, ull* __restrict__ nzmask,
                 const ull* __restrict__ alive_ws,
                 u32* __restrict__ flags, u32* __restrict__ ticket4,
                 float* __restrict__ out)
{
    const int b  = blockIdx.y;
    if (flags[b] == 1u) return;            // hot path: scanA already succeeded

    const int jj = blockIdx.x;             // word-block 0..NW-1
    const int t  = threadIdx.x;

    __shared__ float4 sbox[NSLOT];         // 96 KB
    __shared__ float  sarea[NSLOT];        // 24 KB
    __shared__ int    picks[PROP];         // 4 KB
    __shared__ u32    nzrows[NZCAP];       // 512 B (unused in <false>, kept for sig)

    const float4* bws_b = boxes_ws + (size_t)b * NSLOT;
    const float*  aws_b = area_ws  + (size_t)b * NSLOT;
    ull* mat_b = mat    + (size_t)b * PRE_NMS * MROW;
    ull* nzm_b = nzmask + (size_t)b * NW;

    // complete word-block jj: rows 0..2047 get words CHUNK_W..93; rows 2048+
    // get words jj..93 (kbeg = max(jj, CHUNK_W)).
    iou_block(bws_b, aws_b, mat_b, nzm_b, jj, max(jj, (int)CHUNK_W), NW, sbox, sarea);
    fence_release_agent();                 // publish mat rows (cold path only)
    if (t == 0) atomicAdd(&ticket4[b], 1u);

    if (jj == 0 && t < 64) {
        // lane 0's spin holds the whole wave (single PC, masked lanes wait)
        if (t == 0) {
            while (atomicAdd(&ticket4[b], 0u) < (u32)NW) __builtin_amdgcn_s_sleep(8);
        }
        fence_acquire_agent();             // see all completed mat rows
        scan_wave<false>(b, t, bws_b, alive_ws, mat_b, nzm_b, out, flags,
                         picks, nzrows, (ull*)nullptr);
    }
}

// ---------------------------------------------------------------------------
// Fallback: round-1 monolithic kernel (used if ws too small). Verified exact.
// ---------------------------------------------------------------------------
__device__ __forceinline__ void hist_add_f(unsigned int* hist, unsigned int bin, bool valid) {
    const int lane = threadIdx.x & 63;
    ull todo = __ballot(valid ? 1 : 0);
    #pragma unroll
    for (int it = 0; it < 3; ++it) {
        if (!todo) return;
        int leader = __ffsll(todo) - 1;
        unsigned int lbin = __shfl(bin, leader);
        ull grp = __ballot((valid && (bin == lbin)) ? 1 : 0);
        if (lane == leader) atomicAdd(&hist[lbin], (unsigned int)__popcll(grp));
        todo &= ~grp;
    }
    if ((todo >> lane) & 1ull) atomicAdd(&hist[bin], 1u);
}

__global__ __launch_bounds__(1024)
void proposal_fallback(const float* __restrict__ rpn_probs,
                       const float* __restrict__ rpn_bbox,
                       const float* __restrict__ anchors,
                       float* __restrict__ out)
{
    const int b    = blockIdx.x;
    const int t    = threadIdx.x;
    const int lane = t & 63;
    const int wv   = t >> 6;

    const float2* __restrict__ probs2 = reinterpret_cast<const float2*>(rpn_probs + (size_t)b * NANCH * 2);
    const float4* __restrict__ bbox4  = reinterpret_cast<const float4*>(rpn_bbox  + (size_t)b * NANCH * 4);
    const float4* __restrict__ anc4   = reinterpret_cast<const float4*>(anchors   + (size_t)b * NANCH * 4);
    float* __restrict__ outb = out + (size_t)b * PROP * 4;

    __shared__ __align__(16) char s_big[NSLOT * 16];
    __shared__ ull          s_alive[96];
    __shared__ unsigned int s_hist[256];
    __shared__ unsigned int s_pref;
    __shared__ unsigned int s_targ;
    __shared__ unsigned int s_cnt;

    ull*    sel   = reinterpret_cast<ull*>(s_big);
    float4* boxes = reinterpret_cast<float4*>(s_big);

    const int ITER = (NANCH + 1023) >> 10;

    if (t == 0) { s_pref = 0u; s_targ = PRE_NMS; s_cnt = 0u; }

    for (int p = 0; p < 4; ++p) {
        if (t < 256) s_hist[t] = 0u;
        __syncthreads();
        const unsigned int pref  = s_pref;
        const int          shift = 8 * (3 - p);
        const unsigned int pmask = (p == 0) ? 0u : (0xFFFFFFFFu << (shift + 8));
        for (int i = 0; i < ITER; ++i) {
            int  n     = (i << 10) + t;
            bool valid = (n < NANCH);
            unsigned int key = 0u;
            if (valid) key = __float_as_uint(probs2[n].y);
            bool match = valid && ((key & pmask) == (pref & pmask));
            hist_add_f(s_hist, (key >> shift) & 0xFFu, match);
        }
        __syncthreads();
        if (t == 0) {
            unsigned int target = s_targ;
            unsigned int acc = 0u;
            int v = 255;
            for (; v >= 0; --v) {
                unsigned int h = s_hist[v];
                if (acc + h >= target) break;
                acc += h;
            }
            if (v < 0) v = 0;
            s_pref = pref | ((unsigned int)v << shift);
            s_targ = target - acc;
        }
        __syncthreads();
    }

    const unsigned int T = s_pref;
    __syncthreads();

    for (int i = 0; i < ITER; ++i) {
        int  n     = (i << 10) + t;
        bool valid = (n < NANCH);
        unsigned int key = 0u;
        if (valid) key = __float_as_uint(probs2[n].y);
        bool selp = valid && (key >= T);
        ull  m    = __ballot(selp ? 1 : 0);
        if (m) {
            int leader = __ffsll(m) - 1;
            unsigned int base = 0u;
            if (lane == leader) base = atomicAdd(&s_cnt, (unsigned int)__popcll(m));
            base = __shfl(base, leader);
            if (selp) {
                unsigned int off = base + (unsigned int)__popcll(m & ((1ull << lane) - 1ull));
                if (off < SORTN) sel[off] = ((ull)(~key) << 32) | (ull)(unsigned int)n;
            }
        }
    }
    __syncthreads();
    const unsigned int C = s_cnt;
    for (int s = (int)C + t; s < SORTN; s += 1024) sel[s] = ~0ull;
    __syncthreads();

    for (unsigned int k = 2; k <= SORTN; k <<= 1) {
        for (unsigned int j = k >> 1; j > 0; j >>= 1) {
            #pragma unroll
            for (int r = 0; r < SORTN / 1024; ++r) {
                int i = (r << 10) + t;
                int l = i ^ (int)j;
                if (l > i) {
                    ull a  = sel[i];
                    ull bq = sel[l];
                    bool up = ((i & (int)k) == 0);
                    if ((a > bq) == up) { sel[i] = bq; sel[l] = a; }
                }
            }
            __syncthreads();
        }
    }

    ull ss[6];
    #pragma unroll
    for (int e = 0; e < 6; ++e) ss[e] = sel[(e << 10) + t];
    __syncthreads();

    float4 rbox[6];
    float  rarea[6];
    #pragma unroll
    for (int e = 0; e < 6; ++e) {
        int s = (e << 10) + t;
        float4 bx = make_float4(0.f, 0.f, 0.f, 0.f);
        bool ok = false;
        if (s < PRE_NMS) {
            unsigned int key = ~(unsigned int)(ss[e] >> 32);
            unsigned int n   = (unsigned int)(ss[e] & 0xFFFFFFFFull);
            float4 a = anc4[n];
            float4 d = bbox4[n];
            float dy = d.x * 0.1f, dx = d.y * 0.1f, dh = d.z * 0.2f, dw = d.w * 0.2f;
            float h  = a.z - a.x;
            float w  = a.w - a.y;
            float cy = a.x + 0.5f * h;
            float cx = a.y + 0.5f * w;
            cy = cy + dy * h;
            cx = cx + dx * w;
            h  = h * expf(dh);
            w  = w * expf(dw);
            float y1 = cy - 0.5f * h;
            float x1 = cx - 0.5f * w;
            float y2 = y1 + h;
            float x2 = x1 + w;
            y1 = fminf(fmaxf(y1, 0.f), 1.f);
            x1 = fminf(fmaxf(x1, 0.f), 1.f);
            y2 = fminf(fmaxf(y2, 0.f), 1.f);
            x2 = fminf(fmaxf(x2, 0.f), 1.f);
            bx = make_float4(y1, x1, y2, x2);
            ok = (key >= SCORE_THRES_BITS);
        }
        rbox[e]  = bx;
        rarea[e] = (bx.z - bx.x) * (bx.w - bx.y);
        boxes[s] = bx;
        ull am = __ballot(ok ? 1 : 0);
        if (lane == 0) s_alive[wv + (e << 4)] = am;
    }

    int emitted = 0;
    for (;;) {
        __syncthreads();
        if (emitted == PROP) break;
        ull w0 = s_alive[lane];
        ull w1 = (lane < 32) ? s_alive[64 + lane] : 0ull;
        ull nz0 = __ballot(w0 != 0ull ? 1 : 0);
        ull nz1 = __ballot(w1 != 0ull ? 1 : 0);
        int pick = -1;
        if (nz0) {
            int wd = __ffsll(nz0) - 1;
            ull wvv = __shfl(w0, wd);
            pick = (wd << 6) + __ffsll(wvv) - 1;
        } else if (nz1) {
            int wd = __ffsll(nz1) - 1;
            ull wvv = __shfl(w1, wd);
            pick = ((wd + 64) << 6) + __ffsll(wvv) - 1;
        }
        if (pick < 0) break;
        __syncthreads();

        if (t < 4) outb[(emitted << 2) + t] = reinterpret_cast<const float*>(s_big)[(pick << 2) + t];

        float4 p = boxes[pick];
        float parea = (p.z - p.x) * (p.w - p.y);
        #pragma unroll
        for (int e = 0; e < 6; ++e) {
            float4 bb  = rbox[e];
            float yy1 = fmaxf(p.x, bb.x);
            float xx1 = fmaxf(p.y, bb.y);
            float yy2 = fminf(p.z, bb.z);
            float xx2 = fminf(p.w, bb.w);
            float ih  = fmaxf(yy2 - yy1, 0.f);
            float iw  = fmaxf(xx2 - xx1, 0.f);
            float inter = ih * iw;
            float denom = ((parea + rarea[e]) - inter) + EPS_F;
            bool  sup   = ((double)inter > M_D * (double)denom);
            ull m = __ballot(sup ? 1 : 0);
            int word = wv + (e << 4);
            if (word == (pick >> 6)) m |= (1ull << (pick & 63));
            if (lane == 0) s_alive[word] &= ~m;
        }
        ++emitted;
    }

    for (int i = (emitted << 2) + t; i < PROP * 4; i += 1024) outb[i] = 0.f;
}

extern "C" void kernel_launch(void* const* d_in, const int* in_sizes, int n_in,
                              void* d_out, int out_size, void* d_ws, size_t ws_size,
                              hipStream_t stream) {
    const float* rpn_probs = (const float*)d_in[0];
    const float* rpn_bbox  = (const float*)d_in[1];
    const float* anchors   = (const float*)d_in[2];
    float* out = (float*)d_out;

    // ws layout:
    //   [0)        boxes   8*6144*16 = 786432
    //   [786432)   areas   8*6144*4  = 196608   -> ends 983040
    //   [983040)   ZERO region (one memset to MAT_OFF):
    //       alive   8*96*8 = 6144   @983040
    //       Tc      32 B            @989184
    //       done    32 B            @989440
    //       cntp    8*64*4 = 2048   @989696
    //       ghist   8*256*4 = 8192  @991744   -> ends 999936
    //       flags   8*4 = 32 B      @999936
    //       binbase 8*132*4 = 4224  @1000448
    //       bincnt  8*132*4 = 4224  @1004672
    //       nzmask  8*94*8 = 6016   @1008896  -> ends 1014912
    //       ticket4 32 B            @1015936
    //   [1MiB)     mat (selbuf aliased at its head, consumed before mat write)
    const size_t BOX_OFF   = 0;
    const size_t AREA_OFF  = 786432;
    const size_t ZERO_OFF  = 983040;
    const size_t ALIVE_OFF = 983040;
    const size_t TC_OFF    = 989184;
    const size_t DONE_OFF  = 989440;
    const size_t CNT_OFF   = 989696;
    const size_t GHIST_OFF = 991744;
    const size_t FLAG_OFF  = 999936;
    const size_t BINB_OFF  = 1000448;
    const size_t BINC_OFF  = 1004672;
    const size_t NZ_OFF    = 1008896;
    const size_t TK4_OFF   = 1015936;
    const size_t MAT_OFF   = 1u << 20;
    const size_t SELB_OFF  = MAT_OFF;
    const size_t WS_NEED   = MAT_OFF + (size_t)BATCH * PRE_NMS * MROW * 8;     // ~37.9 MB

    if (d_ws != nullptr && ws_size >= WS_NEED) {
        char* ws = (char*)d_ws;
        float4* boxes_ws = (float4*)(ws + BOX_OFF);
        float*  area_ws  = (float*)(ws + AREA_OFF);
        ull*    alive_ws = (ull*)(ws + ALIVE_OFF);
        u32*    Tc       = (u32*)(ws + TC_OFF);
        u32*    done     = (u32*)(ws + DONE_OFF);
        u32*    cntp     = (u32*)(ws + CNT_OFF);
        u32*    ghist    = (u32*)(ws + GHIST_OFF);
        u32*    flags    = (u32*)(ws + FLAG_OFF);
        u32*    binbase  = (u32*)(ws + BINB_OFF);
        u32*    bincnt   = (u32*)(ws + BINC_OFF);
        ull*    nzmask   = (ull*)(ws + NZ_OFF);
        u32*    ticket4  = (u32*)(ws + TK4_OFF);
        ull*    selbuf   = (ull*)(ws + SELB_OFF);
        ull*    mat      = (ull*)(ws + MAT_OFF);

        hipMemsetAsync(ws + ZERO_OFF, 0, MAT_OFF - ZERO_OFF, stream);  // alive..ticket4
        hipLaunchKernelGGL(hist_kernel, dim3(CBLK, BATCH), dim3(512), 0, stream,
                           rpn_probs, ghist, done, Tc, binbase, cntp);
        hipLaunchKernelGGL(compact_kernel, dim3(CBLK, BATCH), dim3(512), 0, stream,
                           rpn_probs, Tc, binbase, bincnt, selbuf);
        hipLaunchKernelGGL(rank_decode_kernel, dim3(SORTN / 256, BATCH), dim3(256), 0, stream,
                           rpn_bbox, anchors, selbuf, cntp, binbase, ghist,
                           boxes_ws, area_ws, alive_ws);
        hipLaunchKernelGGL(iou_chunk_kernel, dim3(CHUNK_W, BATCH), dim3(1024), 0, stream,
                           boxes_ws, area_ws, mat, nzmask);
        hipLaunchKernelGGL(scanA_kernel, dim3(BATCH), dim3(64), 0, stream,
                           boxes_ws, alive_ws, mat, nzmask, out, flags);
        // merged guarded completion (hot path: flag load + return)
        hipLaunchKernelGGL(rest_kernel, dim3(NW, BATCH), dim3(1024), 0, stream,
                           boxes_ws, area_ws, mat, nzmask, alive_ws,
                           flags, ticket4, out);
    } else {
        hipLaunchKernelGGL(proposal_fallback, dim3(BATCH), dim3(1024), 0, stream,
                           rpn_probs, rpn_bbox, anchors, out);
    }
}